// Round 11
// baseline (571.464 us; speedup 1.0000x reference)
//
#include <hip/hip_runtime.h>
#include <hip/hip_fp16.h>

#define F_IN 1433
#define BCAP 96        // bucket capacity; deg ~ Poisson(32), P(>96) ~ 1e-18
#define KSTR 1480      // LDS Wt row stride in halfs: 740 dwords % 32 = 4 -> 2-way max

// edge_index int32: src = ei[0:E], dst = ei[E:2E]

typedef _Float16 f16x8 __attribute__((ext_vector_type(8)));
typedef float    f32x4 __attribute__((ext_vector_type(4)));

__global__ __launch_bounds__(256) void k_zero(int* __restrict__ p, int n) {
    int i = blockIdx.x * 256 + threadIdx.x;
    if (i < n) p[i] = 0;
}

// histogram + bucket scatter in one pass
__global__ __launch_bounds__(256) void k_scatter(const int* __restrict__ ei,
    int* cnt, int* bucket, int E, int N)
{
    int e = blockIdx.x * 256 + threadIdx.x;
    if (e < E) {
        int s = ei[e], d = ei[E + e];
        if ((unsigned)s < (unsigned)N && (unsigned)d < (unsigned)N) {
            int slot = atomicAdd(&cnt[d], 1);
            if (slot < BCAP) bucket[(size_t)d * BCAP + slot] = s;
        }
    }
}

// ---------------- layer-1 GEMM via MFMA: s1 = rsqrt(cnt+1) * (x @ W1) ----------------
// TWO 16-row tiles per wave (shared B fragment), K in chunks of 32 via mfma_f32_16x16x32_f16.
// Per chunk: 4 independent dwordx4 global loads + 1 ds_read_b128 + 2 MFMA -> deep MLP.
__global__ __launch_bounds__(256) void k_gemm(
    const float* __restrict__ x, const float* __restrict__ W1,
    const int* __restrict__ cnt, float* __restrict__ s, int N)
{
    __shared__ _Float16 wt[16 * KSTR];   // Wt[c][k], zero-padded to 1472; 47360 B
    int tid = threadIdx.x;
    for (int i = tid; i < 16 * 1472; i += 256) {
        int c = i & 15, k = i >> 4;
        float v = (k < F_IN) ? W1[k * 16 + c] : 0.0f;
        wt[c * KSTR + k] = (_Float16)v;
    }
    __syncthreads();

    int wv = tid >> 6, lane = tid & 63;
    int npairs = (N + 31) >> 5;
    int pair = blockIdx.x * 4 + wv;
    if (pair >= npairs) return;

    int rc = lane & 15;          // A-row within tile, and B/D column
    int g  = lane >> 4;          // k-group
    int rowA = pair * 32 + rc;
    int rowB = rowA + 16;
    const float* xr0 = x + (size_t)((rowA < N) ? rowA : (N - 1)) * F_IN;
    const float* xr1 = x + (size_t)((rowB < N) ? rowB : (N - 1)) * F_IN;
    const _Float16* wrow = wt + rc * KSTR;

    struct __attribute__((packed, aligned(4))) f4u { float f[4]; };

    f32x4 acc0 = {0.0f, 0.0f, 0.0f, 0.0f};
    f32x4 acc1 = {0.0f, 0.0f, 0.0f, 0.0f};
    int kb = g * 8;

    #pragma unroll 2
    for (int ch = 0; ch < 44; ++ch) {       // full chunks: k0 = ch*32 + g*8
        int k0 = ch * 32 + kb;
        f4u xa0 = *(const f4u*)&xr0[k0];
        f4u xb0 = *(const f4u*)&xr0[k0 + 4];
        f4u xa1 = *(const f4u*)&xr1[k0];
        f4u xb1 = *(const f4u*)&xr1[k0 + 4];
        f16x8 bv = *(const f16x8*)&wrow[k0];   // shared by both tiles
        f16x8 av0, av1;
        #pragma unroll
        for (int j = 0; j < 4; ++j) {
            av0[j]     = (_Float16)xa0.f[j];
            av0[j + 4] = (_Float16)xb0.f[j];
            av1[j]     = (_Float16)xa1.f[j];
            av1[j + 4] = (_Float16)xb1.f[j];
        }
        acc0 = __builtin_amdgcn_mfma_f32_16x16x32_f16(av0, bv, acc0, 0, 0, 0);
        acc1 = __builtin_amdgcn_mfma_f32_16x16x32_f16(av1, bv, acc1, 0, 0, 0);
    }
    {   // tail chunk: k0 = 1408 + g*8, elements k >= F_IN are zero (guarded)
        int k0 = 1408 + kb;
        f16x8 av0, av1, bv;
        bv = *(const f16x8*)&wrow[k0];      // LDS zero-padded
        #pragma unroll
        for (int j = 0; j < 8; ++j) {
            int k = k0 + j;
            bool ok = k < F_IN;
            av0[j] = (_Float16)(ok ? xr0[k] : 0.0f);
            av1[j] = (_Float16)(ok ? xr1[k] : 0.0f);
        }
        acc0 = __builtin_amdgcn_mfma_f32_16x16x32_f16(av0, bv, acc0, 0, 0, 0);
        acc1 = __builtin_amdgcn_mfma_f32_16x16x32_f16(av1, bv, acc1, 0, 0, 0);
    }

    #pragma unroll
    for (int r = 0; r < 4; ++r) {           // C/D: col=lane&15, row=(lane>>4)*4+reg
        int growA = pair * 32 + g * 4 + r;
        int growB = growA + 16;
        if (growA < N) {
            float di = rsqrtf((float)cnt[growA] + 1.0f);
            s[growA * 16 + rc] = acc0[r] * di;
        }
        if (growB < N) {
            float di = rsqrtf((float)cnt[growB] + 1.0f);
            s[growB * 16 + rc] = acc1[r] * di;
        }
    }
}

// ------- aggA: conv1-agg + b1 + relu + @W2 + dinv  (s1[16] -> s2[16]) -------
// one wave per dst; bucket row in regs, src via shfl; 8 gathers in flight per iter
__global__ __launch_bounds__(256) void k_aggA(
    const int* __restrict__ cnt, const int* __restrict__ bucket,
    const float* __restrict__ sin, const float* __restrict__ W,
    const float* __restrict__ bias, float* __restrict__ sout, int N)
{
    __shared__ float w[256], bs[16];
    int tid = threadIdx.x;
    w[tid] = W[tid];
    if (tid < 16) bs[tid] = bias[tid];
    __syncthreads();

    int wave = tid >> 6, lane = tid & 63;
    int dst = blockIdx.x * 4 + wave;
    if (dst >= N) return;
    int g = lane >> 4, c = lane & 15;
    int deg = min(cnt[dst], BCAP);
    const int* bk = bucket + (size_t)dst * BCAP;

    int e0 = (lane < deg)      ? bk[lane]      : 0;
    int e1 = (64 + lane < deg) ? bk[64 + lane] : 0;

    float acc = (g == 0) ? sin[dst * 16 + c] : 0.0f;     // self-loop
    for (int base = 0; base < deg; base += 32) {         // 8 gathers per iter
        float vs = 0.0f;
        #pragma unroll
        for (int i = 0; i < 8; ++i) {
            int j = base + g + 4 * i;
            int sa = __shfl(e0, j & 63, 64), sb = __shfl(e1, j & 63, 64);
            int sv = (j < 64) ? sa : sb;
            float v = (j < deg) ? sin[sv * 16 + c] : 0.0f;
            vs += v;
        }
        acc += vs;
    }
    acc += __shfl_xor(acc, 16, 64);
    acc += __shfl_xor(acc, 32, 64);

    float di = rsqrtf((float)cnt[dst] + 1.0f);
    float h = fmaxf(fmaf(di, acc, bs[c]), 0.0f);
    float t = 0.0f;
    #pragma unroll
    for (int k = 0; k < 16; ++k)
        t = fmaf(__shfl(h, k, 16), w[k * 16 + c], t);
    if (lane < 16) sout[dst * 16 + c] = di * t;
}

// ------- aggB: conv2-agg + b2 + relu + @W3 + dinv  (s2[16] -> s3[7]) -------
__global__ __launch_bounds__(256) void k_aggB(
    const int* __restrict__ cnt, const int* __restrict__ bucket,
    const float* __restrict__ sin, const float* __restrict__ W,
    const float* __restrict__ bias, float* __restrict__ sout, int N)
{
    __shared__ float w[112], bs[16];
    int tid = threadIdx.x;
    if (tid < 112) w[tid] = W[tid];
    if (tid < 16) bs[tid] = bias[tid];
    __syncthreads();

    int wave = tid >> 6, lane = tid & 63;
    int dst = blockIdx.x * 4 + wave;
    if (dst >= N) return;
    int g = lane >> 4, c = lane & 15;
    int deg = min(cnt[dst], BCAP);
    const int* bk = bucket + (size_t)dst * BCAP;

    int e0 = (lane < deg)      ? bk[lane]      : 0;
    int e1 = (64 + lane < deg) ? bk[64 + lane] : 0;

    float acc = (g == 0) ? sin[dst * 16 + c] : 0.0f;
    for (int base = 0; base < deg; base += 32) {
        float vs = 0.0f;
        #pragma unroll
        for (int i = 0; i < 8; ++i) {
            int j = base + g + 4 * i;
            int sa = __shfl(e0, j & 63, 64), sb = __shfl(e1, j & 63, 64);
            int sv = (j < 64) ? sa : sb;
            float v = (j < deg) ? sin[sv * 16 + c] : 0.0f;
            vs += v;
        }
        acc += vs;
    }
    acc += __shfl_xor(acc, 16, 64);
    acc += __shfl_xor(acc, 32, 64);

    float di = rsqrtf((float)cnt[dst] + 1.0f);
    float h = fmaxf(fmaf(di, acc, bs[c]), 0.0f);
    int cc = (c < 7) ? c : 0;
    float t = 0.0f;
    #pragma unroll
    for (int k = 0; k < 16; ++k)
        t = fmaf(__shfl(h, k, 16), w[k * 7 + cc], t);
    if (lane < 7) sout[dst * 7 + c] = di * t;
}

// ------- aggC: conv3-agg + b3 + log_softmax  (s3[7] -> out[7]) -------
// 8 groups x 8 channel-lanes; 8 gathers in flight per iter
__global__ __launch_bounds__(256) void k_aggC(
    const int* __restrict__ cnt, const int* __restrict__ bucket,
    const float* __restrict__ sin, const float* __restrict__ bias,
    float* __restrict__ out, int N)
{
    __shared__ float bs[8];
    int tid = threadIdx.x;
    if (tid < 7) bs[tid] = bias[tid];
    if (tid == 7) bs[7] = 0.0f;
    __syncthreads();

    int wave = tid >> 6, lane = tid & 63;
    int dst = blockIdx.x * 4 + wave;
    if (dst >= N) return;
    int g8 = lane >> 3, c8 = lane & 7;
    bool c7 = (c8 < 7);
    int cc = c7 ? c8 : 0;
    int deg = min(cnt[dst], BCAP);
    const int* bk = bucket + (size_t)dst * BCAP;

    int e0 = (lane < deg)      ? bk[lane]      : 0;
    int e1 = (64 + lane < deg) ? bk[64 + lane] : 0;

    float acc = (g8 == 0 && c7) ? sin[dst * 7 + c8] : 0.0f;
    for (int base = 0; base < deg; base += 64) {
        float vs = 0.0f;
        #pragma unroll
        for (int i = 0; i < 8; ++i) {
            int j = base + g8 + 8 * i;
            int sa = __shfl(e0, j & 63, 64), sb = __shfl(e1, j & 63, 64);
            int sv = (j < 64) ? sa : sb;
            float v = (j < deg && c7) ? sin[sv * 7 + cc] : 0.0f;
            vs += v;
        }
        acc += vs;
    }
    acc += __shfl_xor(acc, 8, 64);
    acc += __shfl_xor(acc, 16, 64);
    acc += __shfl_xor(acc, 32, 64);

    if (lane < 8) {
        float di = rsqrtf((float)cnt[dst] + 1.0f);
        float logit = c7 ? fmaf(di, acc, bs[c8]) : -1e30f;
        float m = logit;
        m = fmaxf(m, __shfl_xor(m, 1, 8));
        m = fmaxf(m, __shfl_xor(m, 2, 8));
        m = fmaxf(m, __shfl_xor(m, 4, 8));
        float e = c7 ? expf(logit - m) : 0.0f;
        float ssum = e;
        ssum += __shfl_xor(ssum, 1, 8);
        ssum += __shfl_xor(ssum, 2, 8);
        ssum += __shfl_xor(ssum, 4, 8);
        if (c7) out[dst * 7 + c8] = logit - m - logf(ssum);
    }
}

extern "C" void kernel_launch(void* const* d_in, const int* in_sizes, int n_in,
                              void* d_out, int out_size, void* d_ws, size_t ws_size,
                              hipStream_t stream)
{
    const float* x  = (const float*)d_in[0];
    const float* W1 = (const float*)d_in[1];
    const float* b1 = (const float*)d_in[2];
    const float* W2 = (const float*)d_in[3];
    const float* b2 = (const float*)d_in[4];
    const float* W3 = (const float*)d_in[5];
    const float* b3 = (const float*)d_in[6];
    const int*   ei = (const int*)d_in[7];
    float* out = (float*)d_out;

    int N = in_sizes[0] / F_IN;
    int E = in_sizes[7] / 2;

    int*   cnt    = (int*)d_ws;                          // N
    int*   bucket = cnt + N;                             // N*BCAP
    float* s1     = (float*)(bucket + (size_t)N * BCAP); // 16N
    float* s2     = s1 + 16 * (size_t)N;                 // 16N
    float* s3     = s2 + 16 * (size_t)N;                 // 7N

    int nbN = (N + 255) / 256;
    int nbE = (E + 255) / 256;
    int nb4 = (N + 3) / 4;
    int npairs = (N + 31) / 32;
    int nbG = (npairs + 3) / 4;

    k_zero   <<<nbN, 256, 0, stream>>>(cnt, N);
    k_scatter<<<nbE, 256, 0, stream>>>(ei, cnt, bucket, E, N);
    k_gemm   <<<nbG, 256, 0, stream>>>(x, W1, cnt, s1, N);
    k_aggA   <<<nb4, 256, 0, stream>>>(cnt, bucket, s1, W2, b1, s2, N);
    k_aggB   <<<nb4, 256, 0, stream>>>(cnt, bucket, s2, W3, b2, s3, N);
    k_aggC   <<<nb4, 256, 0, stream>>>(cnt, bucket, s3, b3, out, N);
}

// Round 12
// 504.220 us; speedup vs baseline: 1.1334x; 1.1334x over previous
//
#include <hip/hip_runtime.h>
#include <hip/hip_fp16.h>

#define F_IN 1433
#define BCAP 96        // bucket capacity; deg ~ Poisson(32), P(>96) ~ 1e-18
#define WSTR 2048      // wt row stride in halfs (global, L2-resident)

// edge_index int32: src = ei[0:E], dst = ei[E:2E]

typedef _Float16 f16x8 __attribute__((ext_vector_type(8)));
typedef float    f32x4 __attribute__((ext_vector_type(4)));

// zero cnt + build fp16 W^T table (wt[c][k], zero-padded) in one node
__global__ __launch_bounds__(256) void k_prep(const float* __restrict__ W1,
    int* __restrict__ cnt, _Float16* __restrict__ wt, int N)
{
    int i = blockIdx.x * 256 + threadIdx.x;
    if (i < N) cnt[i] = 0;
    if (i < 16 * WSTR) {
        int c = i >> 11, k = i & (WSTR - 1);
        float v = (k < F_IN) ? W1[k * 16 + c] : 0.0f;
        wt[i] = (_Float16)v;
    }
}

// histogram + bucket scatter in one pass
__global__ __launch_bounds__(256) void k_scatter(const int* __restrict__ ei,
    int* cnt, int* bucket, int E, int N)
{
    int e = blockIdx.x * 256 + threadIdx.x;
    if (e < E) {
        int s = ei[e], d = ei[E + e];
        if ((unsigned)s < (unsigned)N && (unsigned)d < (unsigned)N) {
            int slot = atomicAdd(&cnt[d], 1);
            if (slot < BCAP) bucket[(size_t)d * BCAP + slot] = s;
        }
    }
}

// ---------------- layer-1 GEMM via MFMA: s1 = rsqrt(cnt+1) * (x @ W1) ----------------
// NO LDS: B fragments stream from the L2-hot wt table -> occupancy is VGPR-bound
// (~5-6 waves/SIMD vs 2 when LDS-staged). One 16-row tile per wave, unroll 4.
__global__ __launch_bounds__(256, 4) void k_gemm(
    const float* __restrict__ x, const _Float16* __restrict__ wt,
    const int* __restrict__ cnt, float* __restrict__ s, int N)
{
    int tid = threadIdx.x;
    int wv = tid >> 6, lane = tid & 63;
    int ntiles = (N + 15) >> 4;
    int tile = blockIdx.x * 4 + wv;
    if (tile >= ntiles) return;

    int rc = lane & 15;          // A-row within tile, and B/D column
    int g  = lane >> 4;          // k-group
    int row = tile * 16 + rc;
    const float* xr = x + (size_t)((row < N) ? row : (N - 1)) * F_IN;
    const _Float16* wrow = wt + (rc << 11);

    struct __attribute__((packed, aligned(4))) f4u { float f[4]; };

    f32x4 acc = {0.0f, 0.0f, 0.0f, 0.0f};
    int kb = g * 8;

    #pragma unroll 4
    for (int ch = 0; ch < 44; ++ch) {       // full chunks: k0 = ch*32 + g*8
        int k0 = ch * 32 + kb;
        f4u xa = *(const f4u*)&xr[k0];
        f4u xb = *(const f4u*)&xr[k0 + 4];
        f16x8 bv = *(const f16x8*)&wrow[k0];   // global, L2-hot, 16B-aligned
        f16x8 av;
        #pragma unroll
        for (int j = 0; j < 4; ++j) {
            av[j]     = (_Float16)xa.f[j];
            av[j + 4] = (_Float16)xb.f[j];
        }
        acc = __builtin_amdgcn_mfma_f32_16x16x32_f16(av, bv, acc, 0, 0, 0);
    }
    {   // tail chunk: k0 = 1408 + g*8, elements k >= F_IN are zero (guarded)
        int k0 = 1408 + kb;
        f16x8 av, bv;
        bv = *(const f16x8*)&wrow[k0];      // table zero-padded
        #pragma unroll
        for (int j = 0; j < 8; ++j) {
            int k = k0 + j;
            av[j] = (_Float16)((k < F_IN) ? xr[k] : 0.0f);
        }
        acc = __builtin_amdgcn_mfma_f32_16x16x32_f16(av, bv, acc, 0, 0, 0);
    }

    #pragma unroll
    for (int r = 0; r < 4; ++r) {           // C/D: col=lane&15, row=(lane>>4)*4+reg
        int grow = tile * 16 + g * 4 + r;
        if (grow < N) {
            float di = rsqrtf((float)cnt[grow] + 1.0f);
            s[grow * 16 + rc] = acc[r] * di;
        }
    }
}

// ------- aggA: conv1-agg + b1 + relu + @W2 + dinv  (s1[16] -> s2[16]) -------
// one wave per dst; bucket row in regs, src via shfl; 8 gathers in flight per iter
__global__ __launch_bounds__(256) void k_aggA(
    const int* __restrict__ cnt, const int* __restrict__ bucket,
    const float* __restrict__ sin, const float* __restrict__ W,
    const float* __restrict__ bias, float* __restrict__ sout, int N)
{
    __shared__ float w[256], bs[16];
    int tid = threadIdx.x;
    w[tid] = W[tid];
    if (tid < 16) bs[tid] = bias[tid];
    __syncthreads();

    int wave = tid >> 6, lane = tid & 63;
    int dst = blockIdx.x * 4 + wave;
    if (dst >= N) return;
    int g = lane >> 4, c = lane & 15;
    int deg = min(cnt[dst], BCAP);
    const int* bk = bucket + (size_t)dst * BCAP;

    int e0 = (lane < deg)      ? bk[lane]      : 0;
    int e1 = (64 + lane < deg) ? bk[64 + lane] : 0;

    float acc = (g == 0) ? sin[dst * 16 + c] : 0.0f;     // self-loop
    for (int base = 0; base < deg; base += 32) {         // 8 gathers per iter
        float vs = 0.0f;
        #pragma unroll
        for (int i = 0; i < 8; ++i) {
            int j = base + g + 4 * i;
            int sa = __shfl(e0, j & 63, 64), sb = __shfl(e1, j & 63, 64);
            int sv = (j < 64) ? sa : sb;
            float v = (j < deg) ? sin[sv * 16 + c] : 0.0f;
            vs += v;
        }
        acc += vs;
    }
    acc += __shfl_xor(acc, 16, 64);
    acc += __shfl_xor(acc, 32, 64);

    float di = rsqrtf((float)cnt[dst] + 1.0f);
    float h = fmaxf(fmaf(di, acc, bs[c]), 0.0f);
    float t = 0.0f;
    #pragma unroll
    for (int k = 0; k < 16; ++k)
        t = fmaf(__shfl(h, k, 16), w[k * 16 + c], t);
    if (lane < 16) sout[dst * 16 + c] = di * t;
}

// ------- aggB: conv2-agg + b2 + relu + @W3 + dinv  (s2[16] -> s3[7]) -------
__global__ __launch_bounds__(256) void k_aggB(
    const int* __restrict__ cnt, const int* __restrict__ bucket,
    const float* __restrict__ sin, const float* __restrict__ W,
    const float* __restrict__ bias, float* __restrict__ sout, int N)
{
    __shared__ float w[112], bs[16];
    int tid = threadIdx.x;
    if (tid < 112) w[tid] = W[tid];
    if (tid < 16) bs[tid] = bias[tid];
    __syncthreads();

    int wave = tid >> 6, lane = tid & 63;
    int dst = blockIdx.x * 4 + wave;
    if (dst >= N) return;
    int g = lane >> 4, c = lane & 15;
    int deg = min(cnt[dst], BCAP);
    const int* bk = bucket + (size_t)dst * BCAP;

    int e0 = (lane < deg)      ? bk[lane]      : 0;
    int e1 = (64 + lane < deg) ? bk[64 + lane] : 0;

    float acc = (g == 0) ? sin[dst * 16 + c] : 0.0f;
    for (int base = 0; base < deg; base += 32) {
        float vs = 0.0f;
        #pragma unroll
        for (int i = 0; i < 8; ++i) {
            int j = base + g + 4 * i;
            int sa = __shfl(e0, j & 63, 64), sb = __shfl(e1, j & 63, 64);
            int sv = (j < 64) ? sa : sb;
            float v = (j < deg) ? sin[sv * 16 + c] : 0.0f;
            vs += v;
        }
        acc += vs;
    }
    acc += __shfl_xor(acc, 16, 64);
    acc += __shfl_xor(acc, 32, 64);

    float di = rsqrtf((float)cnt[dst] + 1.0f);
    float h = fmaxf(fmaf(di, acc, bs[c]), 0.0f);
    int cc = (c < 7) ? c : 0;
    float t = 0.0f;
    #pragma unroll
    for (int k = 0; k < 16; ++k)
        t = fmaf(__shfl(h, k, 16), w[k * 7 + cc], t);
    if (lane < 7) sout[dst * 7 + c] = di * t;
}

// ------- aggC: conv3-agg + b3 + log_softmax  (s3[7] -> out[7]) -------
__global__ __launch_bounds__(256) void k_aggC(
    const int* __restrict__ cnt, const int* __restrict__ bucket,
    const float* __restrict__ sin, const float* __restrict__ bias,
    float* __restrict__ out, int N)
{
    __shared__ float bs[8];
    int tid = threadIdx.x;
    if (tid < 7) bs[tid] = bias[tid];
    if (tid == 7) bs[7] = 0.0f;
    __syncthreads();

    int wave = tid >> 6, lane = tid & 63;
    int dst = blockIdx.x * 4 + wave;
    if (dst >= N) return;
    int g8 = lane >> 3, c8 = lane & 7;
    bool c7 = (c8 < 7);
    int cc = c7 ? c8 : 0;
    int deg = min(cnt[dst], BCAP);
    const int* bk = bucket + (size_t)dst * BCAP;

    int e0 = (lane < deg)      ? bk[lane]      : 0;
    int e1 = (64 + lane < deg) ? bk[64 + lane] : 0;

    float acc = (g8 == 0 && c7) ? sin[dst * 7 + c8] : 0.0f;
    for (int base = 0; base < deg; base += 64) {
        float vs = 0.0f;
        #pragma unroll
        for (int i = 0; i < 8; ++i) {
            int j = base + g8 + 8 * i;
            int sa = __shfl(e0, j & 63, 64), sb = __shfl(e1, j & 63, 64);
            int sv = (j < 64) ? sa : sb;
            float v = (j < deg && c7) ? sin[sv * 7 + cc] : 0.0f;
            vs += v;
        }
        acc += vs;
    }
    acc += __shfl_xor(acc, 8, 64);
    acc += __shfl_xor(acc, 16, 64);
    acc += __shfl_xor(acc, 32, 64);

    if (lane < 8) {
        float di = rsqrtf((float)cnt[dst] + 1.0f);
        float logit = c7 ? fmaf(di, acc, bs[c8]) : -1e30f;
        float m = logit;
        m = fmaxf(m, __shfl_xor(m, 1, 8));
        m = fmaxf(m, __shfl_xor(m, 2, 8));
        m = fmaxf(m, __shfl_xor(m, 4, 8));
        float e = c7 ? expf(logit - m) : 0.0f;
        float ssum = e;
        ssum += __shfl_xor(ssum, 1, 8);
        ssum += __shfl_xor(ssum, 2, 8);
        ssum += __shfl_xor(ssum, 4, 8);
        if (c7) out[dst * 7 + c8] = logit - m - logf(ssum);
    }
}

extern "C" void kernel_launch(void* const* d_in, const int* in_sizes, int n_in,
                              void* d_out, int out_size, void* d_ws, size_t ws_size,
                              hipStream_t stream)
{
    const float* x  = (const float*)d_in[0];
    const float* W1 = (const float*)d_in[1];
    const float* b1 = (const float*)d_in[2];
    const float* W2 = (const float*)d_in[3];
    const float* b2 = (const float*)d_in[4];
    const float* W3 = (const float*)d_in[5];
    const float* b3 = (const float*)d_in[6];
    const int*   ei = (const int*)d_in[7];
    float* out = (float*)d_out;

    int N = in_sizes[0] / F_IN;
    int E = in_sizes[7] / 2;

    int*      cnt    = (int*)d_ws;                           // N
    int*      bucket = cnt + N;                              // N*BCAP
    _Float16* wt     = (_Float16*)(bucket + (size_t)N * BCAP); // 16*WSTR halfs (64KB)
    float*    s1     = (float*)(wt + 16 * WSTR);             // 16N
    float*    s2     = s1 + 16 * (size_t)N;                  // 16N
    float*    s3     = s2 + 16 * (size_t)N;                  // 7N

    int nbN = (N + 255) / 256;
    int nbE = (E + 255) / 256;
    int nb4 = (N + 3) / 4;
    int ntiles = (N + 15) / 16;
    int nbG = (ntiles + 3) / 4;

    k_prep   <<<nbN, 256, 0, stream>>>(W1, cnt, wt, N);
    k_scatter<<<nbE, 256, 0, stream>>>(ei, cnt, bucket, E, N);
    k_gemm   <<<nbG, 256, 0, stream>>>(x, wt, cnt, s1, N);
    k_aggA   <<<nb4, 256, 0, stream>>>(cnt, bucket, s1, W2, b1, s2, N);
    k_aggB   <<<nb4, 256, 0, stream>>>(cnt, bucket, s2, W3, b2, s3, N);
    k_aggC   <<<nb4, 256, 0, stream>>>(cnt, bucket, s3, b3, out, N);
}